// Round 3
// baseline (169.137 us; speedup 1.0000x reference)
//
#include <hip/hip_runtime.h>

#define OUT_F 11008
#define IN_F  4096
#define PKW   2048   // int32 words per weight row (each word = 1 byte = 2 nibbles)
#define BLKQ  128

typedef __attribute__((ext_vector_type(8))) short          s16x8;
typedef __attribute__((ext_vector_type(8))) unsigned short u16x8;
typedef __attribute__((ext_vector_type(4))) float          f32x4;
typedef __attribute__((ext_vector_type(4))) int            i32x4;

__device__ __forceinline__ unsigned short f2bf(float f) {
    union { float f; unsigned u; } v; v.f = f;
    unsigned r = v.u + 0x8000u + ((v.u >> 16) & 1u);   // RNE-ish
    return (unsigned short)(r >> 16);
}

// Pre-swizzle x (64x4096 f32) into MFMA A-fragment order (bf16):
//   xf[((kb*4 + mt)*64 + lane)*8 + i] = x[mt*16 + (lane&15)][kb*32 + (lane>>4)*8 + i]
__global__ void prep_xfrag(const float* __restrict__ x, unsigned short* __restrict__ xf) {
    int kb   = blockIdx.x;            // 0..127 (k-window of 32)
    int t    = threadIdx.x;           // 0..255
    int mt   = t >> 6;
    int lane = t & 63;
    int m  = mt * 16 + (lane & 15);
    int k0 = kb * 32 + (lane >> 4) * 8;
    const float* xp = x + m * IN_F + k0;
    f32x4 a = *(const f32x4*)(xp);
    f32x4 b = *(const f32x4*)(xp + 4);
    u16x8 v;
    v[0] = f2bf(a[0]); v[1] = f2bf(a[1]); v[2] = f2bf(a[2]); v[3] = f2bf(a[3]);
    v[4] = f2bf(b[0]); v[5] = f2bf(b[1]); v[6] = f2bf(b[2]); v[7] = f2bf(b[3]);
    *(u16x8*)(xf + (size_t)((kb * 4 + mt) * 64 + lane) * 8) = v;
}

// Main: one WG (512 thr = 8 waves) per 16 output cols.
// Wave w = (kh = w>>2, ph = w&3) handles windows {kh*64 + ph + 4t : t=0..15}.
// PHASE-LOCKING (windows stride 4) makes each lane's (k mod 128) constant, so
// the dequant-constant table is 8 (s,zs) pairs = 16 VGPR instead of 64.
// Everything lives in NAMED scalar registers (no demotion risk, ~100 VGPR ->
// 4 waves/SIMD with launch_bounds(512,4)); 8 waves/WG doubles TLP vs the
// 4-wave version; no barriers in the main loop; A-frag loads are issued
// BEFORE weight prefetches each step so counted vmcnt waits never drain the
// 4-window-deep weight prefetch queue.
__global__ __launch_bounds__(512, 4) void qlin_main(
    const int*   __restrict__ wq,
    const float* __restrict__ scale,
    const float* __restrict__ zp,
    const float* __restrict__ bias,
    const unsigned short* __restrict__ xf,
    float* __restrict__ out)
{
    __shared__ float lsum[8 * 1024];   // 32 KB: 8 waves x (64 m x 16 col)

    const int t      = threadIdx.x;
    const int o_base = blockIdx.x * 16;
    const int wave   = t >> 6;        // 0..7
    const int lane   = t & 63;
    const int o_r    = lane & 15;     // output col within tile (B-frag col)
    const int quad   = lane >> 4;     // k-quad within 32-k window
    const int o      = o_base + o_r;
    const int kh     = wave >> 2;     // K-half
    const int ph     = wave & 3;      // phase: window mod 4

    // dequant constants for this lane's FIXED j = ph*32 + quad*8 + i, i=0..7
    float s[8], zs[8];
    {
        const float* sp  = scale + (size_t)o * BLKQ + ph * 32 + quad * 8;
        const float* zpp = zp    + (size_t)o * BLKQ + ph * 32 + quad * 8;
        f32x4 s0 = *(const f32x4*)(sp);
        f32x4 s1 = *(const f32x4*)(sp + 4);
        f32x4 z0 = *(const f32x4*)(zpp);
        f32x4 z1 = *(const f32x4*)(zpp + 4);
        #pragma unroll
        for (int i = 0; i < 4; ++i) {
            s [i]     = s0[i];  zs[i]     = z0[i] * s0[i];
            s [i + 4] = s1[i];  zs[i + 4] = z1[i] * s1[i];
        }
    }

    // wave's first window w0 = kh*64 + ph; per step t' the window advances by 4.
    // weight dwords: o*2048 + window*16 + quad*4 -> stride 64 dwords per step.
    const int* wqp = wq + (size_t)o * PKW + (kh * 64 + ph) * 16 + quad * 4;
    // A-frags (s16x8 units): (window*4 + mt)*64 + lane -> stride 1024 per step.
    const s16x8* xfp = (const s16x8*)xf + (size_t)(kh * 64 + ph) * 256 + lane;

    f32x4 acc0 = {0.f,0.f,0.f,0.f}, acc1 = acc0, acc2 = acc0, acc3 = acc0;
    s16x8 afA0, afA1, afA2, afA3, afB0, afB1, afB2, afB3;
    i32x4 wg0, wg1, wg2, wg3;

    // prologue: A-frags for steps 0,1 FIRST (so later waits on them never
    // drain newer weight loads), then 4-deep weight prefetch.
    afA0 = xfp[0];    afA1 = xfp[64];        afA2 = xfp[128];        afA3 = xfp[192];
    afB0 = xfp[1024]; afB1 = xfp[1024 + 64]; afB2 = xfp[1024 + 128]; afB3 = xfp[1024 + 192];
    wg0 = *(const i32x4*)(wqp);
    wg1 = *(const i32x4*)(wqp + 64);
    wg2 = *(const i32x4*)(wqp + 128);
    wg3 = *(const i32x4*)(wqp + 192);

    // One step: dequant wg##J (8 nibbles, fixed s/zs), 4 MFMAs on A0..A3,
    // then refill A-frags (step tp+J+2) and weight ring (step tp+J+4).
#define SUB(J, A0, A1, A2, A3) do {                                              \
        s16x8 bfr;                                                               \
        _Pragma("unroll")                                                        \
        for (int d = 0; d < 4; ++d) {                                            \
            unsigned dw = (unsigned)wg##J[d];                                    \
            float fh = (float)((dw >> 4) & 15u);   /* k even (high nibble) */    \
            float fl = (float)(dw & 15u);          /* k odd */                   \
            bfr[2 * d]     = (short)f2bf(fmaf(fh, s[2 * d],     -zs[2 * d]));    \
            bfr[2 * d + 1] = (short)f2bf(fmaf(fl, s[2 * d + 1], -zs[2 * d + 1]));\
        }                                                                        \
        acc0 = __builtin_amdgcn_mfma_f32_16x16x32_bf16(A0, bfr, acc0, 0, 0, 0);  \
        acc1 = __builtin_amdgcn_mfma_f32_16x16x32_bf16(A1, bfr, acc1, 0, 0, 0);  \
        acc2 = __builtin_amdgcn_mfma_f32_16x16x32_bf16(A2, bfr, acc2, 0, 0, 0);  \
        acc3 = __builtin_amdgcn_mfma_f32_16x16x32_bf16(A3, bfr, acc3, 0, 0, 0);  \
        if (tp + (J) + 2 < 16) {                                                 \
            const s16x8* ap_ = xfp + (size_t)(tp + (J) + 2) * 1024;              \
            A0 = ap_[0]; A1 = ap_[64]; A2 = ap_[128]; A3 = ap_[192];             \
        }                                                                        \
        if (tp + (J) + 4 < 16) {                                                 \
            wg##J = *(const i32x4*)(wqp + (tp + (J) + 4) * 64);                  \
        }                                                                        \
    } while (0)

    for (int tp = 0; tp < 16; tp += 4) {
        SUB(0, afA0, afA1, afA2, afA3);
        SUB(1, afB0, afB1, afB2, afB3);
        SUB(2, afA0, afA1, afA2, afA3);
        SUB(3, afB0, afB1, afB2, afB3);
    }
#undef SUB

    // 8-way K-piece reduction via LDS, add bias, store
    {
        const int mb = quad * 4;
#define STACC(MT, A)                                                  \
        lsum[wave * 1024 + ((MT) * 16 + mb + 0) * 16 + o_r] = A[0];   \
        lsum[wave * 1024 + ((MT) * 16 + mb + 1) * 16 + o_r] = A[1];   \
        lsum[wave * 1024 + ((MT) * 16 + mb + 2) * 16 + o_r] = A[2];   \
        lsum[wave * 1024 + ((MT) * 16 + mb + 3) * 16 + o_r] = A[3];
        STACC(0, acc0) STACC(1, acc1) STACC(2, acc2) STACC(3, acc3)
#undef STACC
    }
    __syncthreads();
    #pragma unroll
    for (int p = 0; p < 2; ++p) {
        int e = p * 512 + t;
        int m = e >> 4, col = e & 15;
        float v = lsum[e]        + lsum[1024 + e] + lsum[2048 + e] + lsum[3072 + e]
                + lsum[4096 + e] + lsum[5120 + e] + lsum[6144 + e] + lsum[7168 + e]
                + bias[o_base + col];
        out[(size_t)m * OUT_F + o_base + col] = v;
    }
}

extern "C" void kernel_launch(void* const* d_in, const int* in_sizes, int n_in,
                              void* d_out, int out_size, void* d_ws, size_t ws_size,
                              hipStream_t stream) {
    const float* x     = (const float*)d_in[0];
    const int*   wq    = (const int*)d_in[1];
    const float* scale = (const float*)d_in[2];
    const float* zpv   = (const float*)d_in[3];
    const float* bias  = (const float*)d_in[4];
    float* out = (float*)d_out;
    unsigned short* xf = (unsigned short*)d_ws;   // 512 KB A-fragment buffer

    prep_xfrag<<<128, 256, 0, stream>>>(x, xf);
    qlin_main<<<OUT_F / 16, 512, 0, stream>>>(wq, scale, zpv, bias, xf, out);
}